// Round 1
// baseline (175.892 us; speedup 1.0000x reference)
//
#include <hip/hip_runtime.h>
#include <float.h>
#include <math.h>

#define NSAMP 100
#define IMG_W 2048
#define IMG_H 2048

__device__ __forceinline__ float bilin(const float* __restrict__ img, float x, float y) {
    // x,y already clipped to [0, 2047] -> floor >= 0
    float x0f = floorf(x), y0f = floorf(y);
    float wx = x - x0f, wy = y - y0f;
    int x0 = (int)x0f;
    int y0 = (int)y0f;
    int x1 = min(x0 + 1, IMG_W - 1);
    int y1 = min(y0 + 1, IMG_H - 1);
    float v00 = img[y0 * IMG_W + x0];
    float v01 = img[y0 * IMG_W + x1];
    float v10 = img[y1 * IMG_W + x0];
    float v11 = img[y1 * IMG_W + x1];
    return v00 * (1.f - wx) * (1.f - wy) + v01 * wx * (1.f - wy)
         + v10 * (1.f - wx) * wy       + v11 * wx * wy;
}

__global__ void zero_accum_kernel(double* accum) {
    *accum = 0.0;
}

__global__ __launch_bounds__(256) void contour_loss_kernel(
        const float* __restrict__ img,
        const float* __restrict__ points,
        const float* __restrict__ normals,
        double* __restrict__ accum, int N) {
    int i = blockIdx.x * blockDim.x + threadIdx.x;
    float sq = 0.f;
    if (i < N) {
        float px = fminf(fmaxf(points[2 * i],     0.f), 2047.f);
        float py = fminf(fmaxf(points[2 * i + 1], 0.f), 2047.f);
        float nx = normals[2 * i];
        float ny = normals[2 * i + 1];
        // d = normalize([-ny, nx])
        float ddx = -ny, ddy = nx;
        float nrm = sqrtf(ddx * ddx + ddy * ddy);
        float dx = ddx / nrm, dy = ddy / nrm;

        const float maxf = FLT_MAX;
        float sdx = (dx != 0.f) ? dx : 1.f;
        float sdy = (dy != 0.f) ? dy : 1.f;
        float t_left   = (dx != 0.f) ? (0.f    - px) / sdx : -maxf;
        float t_right  = (dx != 0.f) ? (2047.f - px) / sdx :  maxf;
        float t_top    = (dy != 0.f) ? (0.f    - py) / sdy : -maxf;
        float t_bottom = (dy != 0.f) ? (2047.f - py) / sdy :  maxf;
        float t_min = fmaxf(t_left, t_top);
        float t_max = fminf(t_right, t_bottom);

        float p1x = px + t_min * dx, p1y = py + t_min * dy;
        float p2x = px + t_max * dx, p2y = py + t_max * dy;
        float vx = p2x - p1x, vy = p2y - p1y;

        // sample s=0
        float lx = fminf(fmaxf(p1x, 0.f), 2047.f);
        float ly = fminf(fmaxf(p1y, 0.f), 2047.f);
        float v_im1 = bilin(img, lx, ly);
        // sample s=1
        float t1 = (float)(1.0 / 99.0);
        lx = fminf(fmaxf(p1x + t1 * vx, 0.f), 2047.f);
        ly = fminf(fmaxf(p1y + t1 * vy, 0.f), 2047.f);
        float v_i = bilin(img, lx, ly);
        float cx = lx, cy = ly;          // line coords at current center sample

        float best_val = v_i;            // argmin over all-inf returns 0 -> vals[1]
        float best_d2  = INFINITY;

        float ref_val = bilin(img, px, py);

        for (int s = 2; s < NSAMP; ++s) {
            // match np.linspace: t = round_f32(s/99) ; endpoint exactly 1.0
            float t = (s == NSAMP - 1) ? 1.0f : (float)((double)s * (1.0 / 99.0));
            float nlx = fminf(fmaxf(p1x + t * vx, 0.f), 2047.f);
            float nly = fminf(fmaxf(p1y + t * vy, 0.f), 2047.f);
            float v_ip1 = bilin(img, nlx, nly);
            // center index = s-1 (valid centers are samples 1..98)
            if (v_i < v_im1 && v_i < v_ip1) {
                float ex = cx - px, ey = cy - py;
                float d2 = ex * ex + ey * ey;
                if (d2 < best_d2) { best_d2 = d2; best_val = v_i; }
            }
            v_im1 = v_i; v_i = v_ip1; cx = nlx; cy = nly;
        }
        float diff = best_val - ref_val;
        sq = diff * diff;
    }

    // wave (64-lane) shuffle reduction
    for (int off = 32; off > 0; off >>= 1)
        sq += __shfl_down(sq, off);
    __shared__ float wsum[4];
    int lane = threadIdx.x & 63;
    int wid  = threadIdx.x >> 6;
    if (lane == 0) wsum[wid] = sq;
    __syncthreads();
    if (threadIdx.x == 0) {
        float bs = wsum[0] + wsum[1] + wsum[2] + wsum[3];
        atomicAdd(accum, (double)bs);
    }
}

__global__ void finalize_kernel(const double* __restrict__ accum,
                                float* __restrict__ out, int N) {
    out[0] = (float)(accum[0] / (double)N);
}

extern "C" void kernel_launch(void* const* d_in, const int* in_sizes, int n_in,
                              void* d_out, int out_size, void* d_ws, size_t ws_size,
                              hipStream_t stream) {
    const float* img     = (const float*)d_in[0];
    const float* points  = (const float*)d_in[1];
    const float* normals = (const float*)d_in[2];
    int N = in_sizes[1] / 2;
    float* out = (float*)d_out;
    double* accum = (double*)d_ws;

    zero_accum_kernel<<<1, 1, 0, stream>>>(accum);
    int block = 256;
    int grid = (N + block - 1) / block;
    contour_loss_kernel<<<grid, block, 0, stream>>>(img, points, normals, accum, N);
    finalize_kernel<<<1, 1, 0, stream>>>(accum, out, N);
}